// Round 9
// baseline (25.365 us; speedup 1.0000x reference)
//
#include <hip/hip_runtime.h>
#include <math.h>

#define NP 196
#define NCLS 10

// Block = 256 threads (4 waves), one image per block, grid = B = 1024.
// r7 structure; change: thr_s eliminated — inner loop reads ONLY e_s[m]
// (1x ds_read_b128 per m, was b128+b64) and recomputes thresholds
// in-register: nm = v_sqrt(em.em); th = c*nm. Discriminates LDS-instr-
// bound vs VALU-bound phase 2.
//  Phase 1 : t<196: expvals e[t] (float4) via __cosf, inv -> LDS.
//  Phase 2 : wave w: m in [49w,49w+49). Full 64-lane utilization:
//            lane owns 3 patches n=lane+64k (0..191); patches 192..195
//            in a strided tail + shfl_xor butterfly (offsets 4..32).
//  Phase 2b: t<196 combines 4 wave-partials, removes self-edge (identical
//            C expression -> identical codegen -> same w), feats -> LDS.
//  Phase 3 : t<160: class j=t>>4, slice s=t&15 dots feat x W, 16-lane reduce.
//  Phase 4 : t<10 computes log_softmax, stores out[b,10].
__global__ __launch_bounds__(256, 4) void quanv_fused_kernel(
    const float* __restrict__ x,    // [B,784]
    const float* __restrict__ phi,  // [B,196,4]
    const float* __restrict__ W,    // [10,784]
    const float* __restrict__ bl,   // [10]
    float* __restrict__ out)        // [B,10]
{
    const int b    = blockIdx.x;
    const int t    = threadIdx.x;
    const int wave = t >> 6;
    const int lane = t & 63;

    const float C_HI = 0.8944271909999159f;  // sqrt(0.8)
    const float C_LO = 0.7071067811865476f;  // sqrt(0.5)

    __shared__ float4 e_s[NP];      // expvals
    __shared__ float  inv_s[NP];    // 1/(||e||+1e-12)
    __shared__ float4 pa_s[4 * NP]; // per-wave partial a
    __shared__ float  pd_s[4 * NP]; // per-wave partial deg
    __shared__ float4 feat_s[NP];
    __shared__ float  logit_s[NCLS];

    const float* xb = x + (size_t)b * 784;
    const float* pb = phi + (size_t)b * 784;

    // ---- Phase 1 ----
    if (t < NP) {
        const int hp = t / 14, wp = t - hp * 14;
        const int r0 = hp * 2, c0 = wp * 2;
        float th0 = xb[r0 * 28 + c0];
        float th1 = xb[r0 * 28 + c0 + 1];
        float th2 = xb[(r0 + 1) * 28 + c0];
        float th3 = xb[(r0 + 1) * 28 + c0 + 1];
        float4 ph = *(const float4*)(pb + t * 4);
        float z0 = __cosf(th0) * __cosf(ph.x);
        float z1 = __cosf(th1) * __cosf(ph.y);
        float z2 = __cosf(th2) * __cosf(ph.z);
        float z3 = __cosf(th3) * __cosf(ph.w);
        float e0 = z0;
        float e1 = e0 * z1;
        float e2 = e1 * z2;
        float e3 = e2 * z3;
        e_s[t] = make_float4(e0, e1, e2, e3);
        float nn = sqrtf(e0 * e0 + e1 * e1 + e2 * e2 + e3 * e3) + 1e-12f;
        inv_s[t] = 1.0f / nn;
    }
    __syncthreads();

    // ---- Phase 2: main (all 64 lanes, 3 patches each) ----
    const int m0 = wave * 49;
    {
        float4 qn[3];
        float4 a[3];
        float  deg[3];
        #pragma unroll
        for (int k = 0; k < 3; ++k) {
            const int n = lane + 64 * k;
            float4 q = e_s[n];
            float iv = inv_s[n];
            qn[k] = make_float4(q.x * iv, q.y * iv, q.z * iv, q.w * iv);
            a[k] = make_float4(0.f, 0.f, 0.f, 0.f);
            deg[k] = 0.f;
        }
        #pragma unroll 7
        for (int m = m0; m < m0 + 49; ++m) {
            float4 em = e_s[m];      // wave-uniform broadcast (only LDS read)
            float nm  = __builtin_amdgcn_sqrtf(
                em.x * em.x + em.y * em.y + em.z * em.z + em.w * em.w);
            float thx = C_HI * nm;
            float thy = C_LO * nm;
            #pragma unroll
            for (int k = 0; k < 3; ++k) {
                float d  = qn[k].x * em.x + qn[k].y * em.y + qn[k].z * em.z + qn[k].w * em.w;
                float ad = fabsf(d);
                float w  = (ad >= thx) ? 1.0f : ((ad >= thy) ? 0.5f : 0.0f);
                deg[k] += w;
                a[k].x += w * em.x;
                a[k].y += w * em.y;
                a[k].z += w * em.z;
                a[k].w += w * em.w;
            }
        }
        #pragma unroll
        for (int k = 0; k < 3; ++k) {
            pa_s[wave * NP + lane + 64 * k] = a[k];
            pd_s[wave * NP + lane + 64 * k] = deg[k];
        }
    }

    // ---- Phase 2 tail: patches 192..195, m-sliced across 16 lane-groups ----
    {
        const int nt    = 192 + (lane & 3);
        const int slice = lane >> 2;
        float4 q = e_s[nt];
        float iv = inv_s[nt];
        float4 qt = make_float4(q.x * iv, q.y * iv, q.z * iv, q.w * iv);
        float4 at = make_float4(0.f, 0.f, 0.f, 0.f);
        float  dt = 0.f;
        for (int m = m0 + slice; m < m0 + 49; m += 16) {
            float4 em = e_s[m];
            float nm  = __builtin_amdgcn_sqrtf(
                em.x * em.x + em.y * em.y + em.z * em.z + em.w * em.w);
            float thx = C_HI * nm;
            float thy = C_LO * nm;
            float d  = qt.x * em.x + qt.y * em.y + qt.z * em.z + qt.w * em.w;
            float ad = fabsf(d);
            float w  = (ad >= thx) ? 1.0f : ((ad >= thy) ? 0.5f : 0.0f);
            dt += w;
            at.x += w * em.x;
            at.y += w * em.y;
            at.z += w * em.z;
            at.w += w * em.w;
        }
        // butterfly over slices (offsets preserve lane&3)
        #pragma unroll
        for (int off = 4; off <= 32; off <<= 1) {
            at.x += __shfl_xor(at.x, off, 64);
            at.y += __shfl_xor(at.y, off, 64);
            at.z += __shfl_xor(at.z, off, 64);
            at.w += __shfl_xor(at.w, off, 64);
            dt   += __shfl_xor(dt,   off, 64);
        }
        if (lane < 4) {
            pa_s[wave * NP + 192 + lane] = at;
            pd_s[wave * NP + 192 + lane] = dt;
        }
    }
    __syncthreads();

    // ---- Phase 2b: combine partials, self-subtract, build feats ----
    if (t < NP) {
        float4 e  = e_s[t];
        float  iv = inv_s[t];
        float4 at = make_float4(0.f, 0.f, 0.f, 0.f);
        float  dt = 0.f;
        #pragma unroll
        for (int w = 0; w < 4; ++w) {
            float4 p = pa_s[w * NP + t];
            at.x += p.x; at.y += p.y; at.z += p.z; at.w += p.w;
            dt += pd_s[w * NP + t];
        }
        // self-edge: identical expression as the loop body -> same w
        float nm  = __builtin_amdgcn_sqrtf(
            e.x * e.x + e.y * e.y + e.z * e.z + e.w * e.w);
        float thx = C_HI * nm;
        float thy = C_LO * nm;
        float qx = e.x * iv, qy = e.y * iv, qz = e.z * iv, qw = e.w * iv;
        float d  = qx * e.x + qy * e.y + qz * e.z + qw * e.w;
        float ad = fabsf(d);
        float w  = (ad >= thx) ? 1.0f : ((ad >= thy) ? 0.5f : 0.0f);
        dt -= w;
        at.x -= w * e.x; at.y -= w * e.y; at.z -= w * e.z; at.w -= w * e.w;
        const float s = 1.0f + dt;   // smooth = I + D - W
        feat_s[t] = make_float4(s * e.x - at.x, s * e.y - at.y,
                                s * e.z - at.z, s * e.w - at.w);
    }
    __syncthreads();

    // ---- Phase 3: logits ----
    if (t < NCLS * 16) {
        const int j  = t >> 4;
        const int sl = t & 15;
        const float4* wr = (const float4*)(W + j * 784);
        float p = 0.f;
        for (int i = sl; i < NP; i += 16) {
            float4 f  = feat_s[i];
            float4 w4 = wr[i];
            p += f.x * w4.x + f.y * w4.y + f.z * w4.z + f.w * w4.w;
        }
        #pragma unroll
        for (int off = 8; off > 0; off >>= 1)
            p += __shfl_down(p, off, 16);
        if (sl == 0) logit_s[j] = p + bl[j];
    }
    __syncthreads();

    // ---- Phase 4: log_softmax ----
    if (t < NCLS) {
        float mx = -INFINITY;
        #pragma unroll
        for (int j = 0; j < NCLS; ++j) mx = fmaxf(mx, logit_s[j]);
        float sum = 0.f;
        #pragma unroll
        for (int j = 0; j < NCLS; ++j) sum += expf(logit_s[j] - mx);
        out[(size_t)b * NCLS + t] = logit_s[t] - mx - logf(sum);
    }
}

extern "C" void kernel_launch(void* const* d_in, const int* in_sizes, int n_in,
                              void* d_out, int out_size, void* d_ws, size_t ws_size,
                              hipStream_t stream) {
    const float* x   = (const float*)d_in[0];   // [B,1,28,28]
    const float* phi = (const float*)d_in[1];   // [B,196,4]
    const float* W   = (const float*)d_in[2];   // [10,784]
    const float* bl  = (const float*)d_in[3];   // [10]
    float* out = (float*)d_out;                 // [B,10]

    const int B = in_sizes[0] / 784;
    quanv_fused_kernel<<<dim3(B), dim3(256), 0, stream>>>(x, phi, W, bl, out);
}

// Round 10
// 24.409 us; speedup vs baseline: 1.0392x; 1.0392x over previous
//
#include <hip/hip_runtime.h>
#include <math.h>

#define NP 196
#define NCLS 10

// Block = 256 threads = 4 waves; each wave processes ONE image end-to-end.
// grid = B/4 = 256 blocks. ZERO barriers, ZERO inter-wave traffic: per-wave
// private LDS slice holds e/inv/thr; partial combine eliminated entirely
// (each wave covers the full m range for its own patches); feats live in
// registers; logits via 64-lane shfl_xor butterfly.
//  Phase 1 : wave computes its 196 patches (3 full passes + 4-lane pass):
//            e (float4), inv, thresholds (sqrt(.8),sqrt(.5))*||e|| -> LDS.
//  Phase 2 : lane owns n=lane+64k (k=0..2), m iterates [0,196): 1x
//            ds_read_b128 + 1x ds_read_b64 per m, 13-VALU pair body
//            (identical to r7). Self-edge removed in-register right after
//            (identical C expression -> same w). Tail patches 192..195:
//            (patch=lane&3, slice=lane>>2) stride m by 16 + butterfly
//            (offsets 4..32 preserve lane&3).
//  Phase 3 : per-lane partial logits vs L2-hot W (float4), 6-hop butterfly.
//  Phase 4 : lanes 0..9 compute log_softmax, write out[img,10].
__global__ __launch_bounds__(256) void quanv_fused_kernel(
    const float* __restrict__ x,    // [B,784]
    const float* __restrict__ phi,  // [B,196,4]
    const float* __restrict__ W,    // [10,784]
    const float* __restrict__ bl,   // [10]
    float* __restrict__ out)        // [B,10]
{
    const int t    = threadIdx.x;
    const int wave = t >> 6;
    const int lane = t & 63;
    const int img  = blockIdx.x * 4 + wave;

    __shared__ float4 e_s[4][NP];    // per-wave expvals
    __shared__ float  inv_s[4][NP];  // 1/(||e||+1e-12)
    __shared__ float2 thr_s[4][NP];  // (sqrt(.8)*nm, sqrt(.5)*nm)

    const float* xb = x + (size_t)img * 784;
    const float* pb = phi + (size_t)img * 784;

    // ---- Phase 1: this wave fills its own LDS slice (no barrier needed:
    //      same-wave DS ops complete in order; lockstep wave64) ----
    #pragma unroll
    for (int pass = 0; pass < 4; ++pass) {
        const int p = lane + 64 * pass;
        if (pass < 3 || lane < 4) {
            const int hp = p / 14, wp = p - hp * 14;
            const int r0 = hp * 2, c0 = wp * 2;
            float th0 = xb[r0 * 28 + c0];
            float th1 = xb[r0 * 28 + c0 + 1];
            float th2 = xb[(r0 + 1) * 28 + c0];
            float th3 = xb[(r0 + 1) * 28 + c0 + 1];
            float4 ph = *(const float4*)(pb + p * 4);
            float z0 = __cosf(th0) * __cosf(ph.x);
            float z1 = __cosf(th1) * __cosf(ph.y);
            float z2 = __cosf(th2) * __cosf(ph.z);
            float z3 = __cosf(th3) * __cosf(ph.w);
            float e0 = z0;
            float e1 = e0 * z1;
            float e2 = e1 * z2;
            float e3 = e2 * z3;
            e_s[wave][p] = make_float4(e0, e1, e2, e3);
            float nn = sqrtf(e0 * e0 + e1 * e1 + e2 * e2 + e3 * e3) + 1e-12f;
            inv_s[wave][p] = 1.0f / nn;
            thr_s[wave][p] = make_float2(0.8944271909999159f * nn,
                                         0.7071067811865476f * nn);
        }
    }

    // ---- Phase 2: main (3 patches per lane, full m range, full sums) ----
    float4 f[3];     // feats in registers
    {
        float4 qn[3];
        float4 a[3];
        float  deg[3];
        #pragma unroll
        for (int k = 0; k < 3; ++k) {
            const int n = lane + 64 * k;
            float4 q = e_s[wave][n];
            float iv = inv_s[wave][n];
            qn[k] = make_float4(q.x * iv, q.y * iv, q.z * iv, q.w * iv);
            a[k] = make_float4(0.f, 0.f, 0.f, 0.f);
            deg[k] = 0.f;
        }
        #pragma unroll 7
        for (int m = 0; m < NP; ++m) {
            float4 em = e_s[wave][m];    // wave-uniform broadcast
            float2 th = thr_s[wave][m];
            #pragma unroll
            for (int k = 0; k < 3; ++k) {
                float d  = qn[k].x * em.x + qn[k].y * em.y + qn[k].z * em.z + qn[k].w * em.w;
                float ad = fabsf(d);
                float w  = (ad >= th.x) ? 1.0f : ((ad >= th.y) ? 0.5f : 0.0f);
                deg[k] += w;
                a[k].x += w * em.x;
                a[k].y += w * em.y;
                a[k].z += w * em.z;
                a[k].w += w * em.w;
            }
        }
        // self-edge subtract (identical expression -> identical w) + feats
        #pragma unroll
        for (int k = 0; k < 3; ++k) {
            const int n = lane + 64 * k;
            float4 e  = e_s[wave][n];
            float  iv = inv_s[wave][n];
            float2 th = thr_s[wave][n];
            float d  = (e.x * iv) * e.x + (e.y * iv) * e.y + (e.z * iv) * e.z + (e.w * iv) * e.w;
            float ad = fabsf(d);
            float w  = (ad >= th.x) ? 1.0f : ((ad >= th.y) ? 0.5f : 0.0f);
            deg[k] -= w;
            a[k].x -= w * e.x; a[k].y -= w * e.y; a[k].z -= w * e.z; a[k].w -= w * e.w;
            const float s = 1.0f + deg[k];   // smooth = I + D - W
            f[k] = make_float4(s * e.x - a[k].x, s * e.y - a[k].y,
                               s * e.z - a[k].z, s * e.w - a[k].w);
        }
    }

    // ---- Phase 2 tail: patches 192..195 (m-sliced, butterfly) ----
    float4 ft;
    const int nt = 192 + (lane & 3);
    {
        const int slice = lane >> 2;
        float4 q = e_s[wave][nt];
        float iv = inv_s[wave][nt];
        float4 qt = make_float4(q.x * iv, q.y * iv, q.z * iv, q.w * iv);
        float4 at = make_float4(0.f, 0.f, 0.f, 0.f);
        float  dt = 0.f;
        for (int m = slice; m < NP; m += 16) {
            float4 em = e_s[wave][m];
            float2 th = thr_s[wave][m];
            float d  = qt.x * em.x + qt.y * em.y + qt.z * em.z + qt.w * em.w;
            float ad = fabsf(d);
            float w  = (ad >= th.x) ? 1.0f : ((ad >= th.y) ? 0.5f : 0.0f);
            dt += w;
            at.x += w * em.x;
            at.y += w * em.y;
            at.z += w * em.z;
            at.w += w * em.w;
        }
        #pragma unroll
        for (int off = 4; off <= 32; off <<= 1) {
            at.x += __shfl_xor(at.x, off, 64);
            at.y += __shfl_xor(at.y, off, 64);
            at.z += __shfl_xor(at.z, off, 64);
            at.w += __shfl_xor(at.w, off, 64);
            dt   += __shfl_xor(dt,   off, 64);
        }
        // self-edge for the tail patch (every lane computes; lanes 0..3 use)
        float2 th = thr_s[wave][nt];
        float d  = qt.x * q.x + qt.y * q.y + qt.z * q.z + qt.w * q.w;
        float ad = fabsf(d);
        float w  = (ad >= th.x) ? 1.0f : ((ad >= th.y) ? 0.5f : 0.0f);
        dt -= w;
        at.x -= w * q.x; at.y -= w * q.y; at.z -= w * q.z; at.w -= w * q.w;
        const float s = 1.0f + dt;
        ft = make_float4(s * q.x - at.x, s * q.y - at.y,
                         s * q.z - at.z, s * q.w - at.w);
    }

    // ---- Phase 3: per-lane partial logits, butterfly reduce ----
    float pj[NCLS];
    #pragma unroll
    for (int j = 0; j < NCLS; ++j) {
        const float4* wr = (const float4*)(W + j * 784);
        float p = 0.f;
        #pragma unroll
        for (int k = 0; k < 3; ++k) {
            const int n = lane + 64 * k;
            float4 w4 = wr[n];
            p += f[k].x * w4.x + f[k].y * w4.y + f[k].z * w4.z + f[k].w * w4.w;
        }
        if (lane < 4) {
            float4 w4 = wr[nt];
            p += ft.x * w4.x + ft.y * w4.y + ft.z * w4.z + ft.w * w4.w;
        }
        pj[j] = p;
    }
    #pragma unroll
    for (int j = 0; j < NCLS; ++j) {
        float v = pj[j];
        #pragma unroll
        for (int off = 32; off > 0; off >>= 1)
            v += __shfl_xor(v, off, 64);
        pj[j] = v;
    }

    // ---- Phase 4: log_softmax (lanes 0..9) ----
    if (lane < NCLS) {
        float lg[NCLS];
        float mx = -INFINITY;
        #pragma unroll
        for (int j = 0; j < NCLS; ++j) {
            lg[j] = pj[j] + bl[j];
            mx = fmaxf(mx, lg[j]);
        }
        float sum = 0.f;
        #pragma unroll
        for (int j = 0; j < NCLS; ++j) sum += expf(lg[j] - mx);
        out[(size_t)img * NCLS + lane] = lg[lane] - mx - logf(sum);
    }
}

extern "C" void kernel_launch(void* const* d_in, const int* in_sizes, int n_in,
                              void* d_out, int out_size, void* d_ws, size_t ws_size,
                              hipStream_t stream) {
    const float* x   = (const float*)d_in[0];   // [B,1,28,28]
    const float* phi = (const float*)d_in[1];   // [B,196,4]
    const float* W   = (const float*)d_in[2];   // [10,784]
    const float* bl  = (const float*)d_in[3];   // [10]
    float* out = (float*)d_out;                 // [B,10]

    const int B = in_sizes[0] / 784;
    quanv_fused_kernel<<<dim3(B / 4), dim3(256), 0, stream>>>(x, phi, W, bl, out);
}

// Round 11
// 22.484 us; speedup vs baseline: 1.1281x; 1.0856x over previous
//
#include <hip/hip_runtime.h>
#include <math.h>

#define NP 196
#define NCLS 10

typedef float v2f __attribute__((ext_vector_type(2)));

// Block = 256 threads (4 waves), one image per block, grid = B = 1024.
// r7 structure + packed-fp32 math via compiler-native v_pk_mul/fma_f32
// (ext_vector float2 + __builtin_elementwise_fma, NO inline asm):
// per-pair VALU 13 -> ~11.
//  Phase 1 : t<196: expvals e[t] (float4) via __cosf, inv, sqrt-scaled
//            thresholds (sh,sl)=(sqrt(.8),sqrt(.5))*||e|| -> LDS.
//  Phase 2 : wave w: m in [49w,49w+49). Full 64-lane utilization:
//            lane owns 3 patches n=lane+64k (0..191); patches 192..195
//            in a strided tail + shfl_xor butterfly (offsets 4..32).
//            Packed dot: pr=(qx*ex,qy*ey); pr=fma((qz,qw),(ez,ew),pr);
//            d=pr.x+pr.y. Edge test |d| >= sh_m / sl_m.
//  Phase 2b: t<196 combines 4 wave-partials, removes self-edge (mirrors
//            the packed rounding order exactly), feats -> LDS.
//  Phase 3 : t<160: class j=t>>4, slice s=t&15, packed dots feat x W,
//            16-lane shfl reduce.
//  Phase 4 : t<10 computes log_softmax, stores out[b,10].
__global__ __launch_bounds__(256, 4) void quanv_fused_kernel(
    const float* __restrict__ x,    // [B,784]
    const float* __restrict__ phi,  // [B,196,4]
    const float* __restrict__ W,    // [10,784]
    const float* __restrict__ bl,   // [10]
    float* __restrict__ out)        // [B,10]
{
    const int b    = blockIdx.x;
    const int t    = threadIdx.x;
    const int wave = t >> 6;
    const int lane = t & 63;

    __shared__ float4 e_s[NP];      // expvals
    __shared__ float  inv_s[NP];    // 1/(||e||+1e-12)
    __shared__ float2 thr_s[NP];    // (sqrt(0.8)*nm, sqrt(0.5)*nm)
    __shared__ float4 pa_s[4 * NP]; // per-wave partial a
    __shared__ float  pd_s[4 * NP]; // per-wave partial deg
    __shared__ float4 feat_s[NP];
    __shared__ float  logit_s[NCLS];

    const float* xb = x + (size_t)b * 784;
    const float* pb = phi + (size_t)b * 784;

    // ---- Phase 1 ----
    if (t < NP) {
        const int hp = t / 14, wp = t - hp * 14;
        const int r0 = hp * 2, c0 = wp * 2;
        float th0 = xb[r0 * 28 + c0];
        float th1 = xb[r0 * 28 + c0 + 1];
        float th2 = xb[(r0 + 1) * 28 + c0];
        float th3 = xb[(r0 + 1) * 28 + c0 + 1];
        float4 ph = *(const float4*)(pb + t * 4);
        float z0 = __cosf(th0) * __cosf(ph.x);
        float z1 = __cosf(th1) * __cosf(ph.y);
        float z2 = __cosf(th2) * __cosf(ph.z);
        float z3 = __cosf(th3) * __cosf(ph.w);
        float e0 = z0;
        float e1 = e0 * z1;
        float e2 = e1 * z2;
        float e3 = e2 * z3;
        e_s[t] = make_float4(e0, e1, e2, e3);
        float nn = sqrtf(e0 * e0 + e1 * e1 + e2 * e2 + e3 * e3) + 1e-12f;
        inv_s[t] = 1.0f / nn;
        thr_s[t] = make_float2(0.8944271909999159f * nn,   // sqrt(0.8)*nm
                               0.7071067811865476f * nn);  // sqrt(0.5)*nm
    }
    __syncthreads();

    // ---- Phase 2: main (all 64 lanes, 3 patches each, packed math) ----
    const int m0 = wave * 49;
    {
        v2f qnA[3], qnB[3], aA[3], aB[3];
        float deg[3];
        #pragma unroll
        for (int k = 0; k < 3; ++k) {
            const int n = lane + 64 * k;
            float4 q = e_s[n];
            float iv = inv_s[n];
            qnA[k] = (v2f){q.x * iv, q.y * iv};
            qnB[k] = (v2f){q.z * iv, q.w * iv};
            aA[k] = (v2f){0.f, 0.f};
            aB[k] = (v2f){0.f, 0.f};
            deg[k] = 0.f;
        }
        #pragma unroll 7
        for (int m = m0; m < m0 + 49; ++m) {
            float4 em = e_s[m];      // wave-uniform broadcast
            float2 th = thr_s[m];
            v2f emA = (v2f){em.x, em.y};
            v2f emB = (v2f){em.z, em.w};
            #pragma unroll
            for (int k = 0; k < 3; ++k) {
                v2f pr = qnA[k] * emA;                              // v_pk_mul_f32
                pr = __builtin_elementwise_fma(qnB[k], emB, pr);    // v_pk_fma_f32
                float d  = pr.x + pr.y;
                float ad = fabsf(d);
                float w  = (ad >= th.x) ? 1.0f : ((ad >= th.y) ? 0.5f : 0.0f);
                deg[k] += w;
                v2f w2 = (v2f){w, w};
                aA[k] = __builtin_elementwise_fma(w2, emA, aA[k]);
                aB[k] = __builtin_elementwise_fma(w2, emB, aB[k]);
            }
        }
        #pragma unroll
        for (int k = 0; k < 3; ++k) {
            pa_s[wave * NP + lane + 64 * k] =
                make_float4(aA[k].x, aA[k].y, aB[k].x, aB[k].y);
            pd_s[wave * NP + lane + 64 * k] = deg[k];
        }
    }

    // ---- Phase 2 tail: patches 192..195, m-sliced across 16 lane-groups ----
    {
        const int nt    = 192 + (lane & 3);
        const int slice = lane >> 2;
        float4 q = e_s[nt];
        float iv = inv_s[nt];
        v2f qtA = (v2f){q.x * iv, q.y * iv};
        v2f qtB = (v2f){q.z * iv, q.w * iv};
        v2f atA = (v2f){0.f, 0.f};
        v2f atB = (v2f){0.f, 0.f};
        float dt = 0.f;
        for (int m = m0 + slice; m < m0 + 49; m += 16) {
            float4 em = e_s[m];
            float2 th = thr_s[m];
            v2f emA = (v2f){em.x, em.y};
            v2f emB = (v2f){em.z, em.w};
            v2f pr = qtA * emA;
            pr = __builtin_elementwise_fma(qtB, emB, pr);
            float d  = pr.x + pr.y;
            float ad = fabsf(d);
            float w  = (ad >= th.x) ? 1.0f : ((ad >= th.y) ? 0.5f : 0.0f);
            dt += w;
            v2f w2 = (v2f){w, w};
            atA = __builtin_elementwise_fma(w2, emA, atA);
            atB = __builtin_elementwise_fma(w2, emB, atB);
        }
        // butterfly over slices (offsets preserve lane&3)
        float ax = atA.x, ay = atA.y, az = atB.x, aw = atB.y;
        #pragma unroll
        for (int off = 4; off <= 32; off <<= 1) {
            ax += __shfl_xor(ax, off, 64);
            ay += __shfl_xor(ay, off, 64);
            az += __shfl_xor(az, off, 64);
            aw += __shfl_xor(aw, off, 64);
            dt += __shfl_xor(dt, off, 64);
        }
        if (lane < 4) {
            pa_s[wave * NP + 192 + lane] = make_float4(ax, ay, az, aw);
            pd_s[wave * NP + 192 + lane] = dt;
        }
    }
    __syncthreads();

    // ---- Phase 2b: combine partials, self-subtract, build feats ----
    if (t < NP) {
        float4 e  = e_s[t];
        float  iv = inv_s[t];
        float2 th = thr_s[t];
        float4 at = make_float4(0.f, 0.f, 0.f, 0.f);
        float  dt = 0.f;
        #pragma unroll
        for (int w = 0; w < 4; ++w) {
            float4 p = pa_s[w * NP + t];
            at.x += p.x; at.y += p.y; at.z += p.z; at.w += p.w;
            dt += pd_s[w * NP + t];
        }
        // self-edge: mirror the packed rounding order exactly:
        // pr.x = fma(qz, ez, qx*ex); pr.y = fma(qw, ew, qy*ey); d = pr.x+pr.y
        float qx = e.x * iv, qy = e.y * iv, qz = e.z * iv, qw = e.w * iv;
        float lo = __builtin_fmaf(qz, e.z, qx * e.x);
        float hi = __builtin_fmaf(qw, e.w, qy * e.y);
        float d  = lo + hi;
        float ad = fabsf(d);
        float w  = (ad >= th.x) ? 1.0f : ((ad >= th.y) ? 0.5f : 0.0f);
        dt -= w;
        at.x -= w * e.x; at.y -= w * e.y; at.z -= w * e.z; at.w -= w * e.w;
        const float s = 1.0f + dt;   // smooth = I + D - W
        feat_s[t] = make_float4(s * e.x - at.x, s * e.y - at.y,
                                s * e.z - at.z, s * e.w - at.w);
    }
    __syncthreads();

    // ---- Phase 3: logits (packed dots) ----
    if (t < NCLS * 16) {
        const int j  = t >> 4;
        const int sl = t & 15;
        const float4* wr = (const float4*)(W + j * 784);
        v2f pp = (v2f){0.f, 0.f};
        for (int i = sl; i < NP; i += 16) {
            float4 f  = feat_s[i];
            float4 w4 = wr[i];
            pp = __builtin_elementwise_fma((v2f){f.x, f.y}, (v2f){w4.x, w4.y}, pp);
            pp = __builtin_elementwise_fma((v2f){f.z, f.w}, (v2f){w4.z, w4.w}, pp);
        }
        float p = pp.x + pp.y;
        #pragma unroll
        for (int off = 8; off > 0; off >>= 1)
            p += __shfl_down(p, off, 16);
        if (sl == 0) logit_s[j] = p + bl[j];
    }
    __syncthreads();

    // ---- Phase 4: log_softmax ----
    if (t < NCLS) {
        float mx = -INFINITY;
        #pragma unroll
        for (int j = 0; j < NCLS; ++j) mx = fmaxf(mx, logit_s[j]);
        float sum = 0.f;
        #pragma unroll
        for (int j = 0; j < NCLS; ++j) sum += expf(logit_s[j] - mx);
        out[(size_t)b * NCLS + t] = logit_s[t] - mx - logf(sum);
    }
}

extern "C" void kernel_launch(void* const* d_in, const int* in_sizes, int n_in,
                              void* d_out, int out_size, void* d_ws, size_t ws_size,
                              hipStream_t stream) {
    const float* x   = (const float*)d_in[0];   // [B,1,28,28]
    const float* phi = (const float*)d_in[1];   // [B,196,4]
    const float* W   = (const float*)d_in[2];   // [10,784]
    const float* bl  = (const float*)d_in[3];   // [10]
    float* out = (float*)d_out;                 // [B,10]

    const int B = in_sizes[0] / 784;
    quanv_fused_kernel<<<dim3(B), dim3(256), 0, stream>>>(x, phi, W, bl, out);
}

// Round 12
// 22.362 us; speedup vs baseline: 1.1343x; 1.0054x over previous
//
#include <hip/hip_runtime.h>
#include <math.h>

#define NP 196
#define NCLS 10

typedef _Float16 h2 __attribute__((ext_vector_type(2)));

#if defined(__has_builtin)
#  if __has_builtin(__builtin_amdgcn_fdot2)
#    define HAVE_FDOT2 1
#  endif
#endif
#ifndef HAVE_FDOT2
#  define HAVE_FDOT2 0
#endif

__device__ __forceinline__ float dot4_h(h2 qa, h2 qb, h2 ea, h2 eb) {
#if HAVE_FDOT2
    return __builtin_amdgcn_fdot2(qb, eb,
               __builtin_amdgcn_fdot2(qa, ea, 0.0f, false), false);
#else
    return (float)qa.x * (float)ea.x + (float)qa.y * (float)ea.y
         + (float)qb.x * (float)eb.x + (float)qb.y * (float)eb.y;
#endif
}

// Block = 256 threads (4 waves), one image per block, grid = B = 1024.
// r7 structure + f16 packed pair body (v_dot2_f32_f16 + v_pk_fma_f16):
// 9 VALU/pair vs 13 scalar-f32.
//  Phase 1 : t<196: expvals e[t] (float4) via __cosf, inv, f16 copy eh,
//            sqrt-scaled thresholds (sqrt(.8),sqrt(.5))*||e|| -> LDS.
//  Phase 2 : wave w: m in [49w,49w+49). lane owns 3 patches n=lane+64k;
//            dot via 2x fdot2 (f16 in, f32 out), edge test on f32 |d| vs
//            f32 thresholds (same compare domain as before), accumulation
//            in f16 (pk_fma); deg in f16 (exact for halves <= 1024).
//            Tail patches 192..195: strided m + shfl_xor butterfly (f32).
//  Phase 2b: t<196 combines 4 f32 partials; self-edge w recomputed via the
//            IDENTICAL fdot2 chain on identical f16 casts -> identical w;
//            subtraction in f32. feats -> LDS.
//  Phase 3 : t<160: class j=t>>4, slice s=t&15 dots feat x W, 16-lane reduce.
//  Phase 4 : t<10 computes log_softmax, stores out[b,10].
__global__ __launch_bounds__(256, 4) void quanv_fused_kernel(
    const float* __restrict__ x,    // [B,784]
    const float* __restrict__ phi,  // [B,196,4]
    const float* __restrict__ W,    // [10,784]
    const float* __restrict__ bl,   // [10]
    float* __restrict__ out)        // [B,10]
{
    const int b    = blockIdx.x;
    const int t    = threadIdx.x;
    const int wave = t >> 6;
    const int lane = t & 63;

    __shared__ float4 e_s[NP];      // expvals (f32)
    __shared__ float  inv_s[NP];    // 1/(||e||+1e-12)
    __shared__ float2 thr_s[NP];    // (sqrt(0.8)*nm, sqrt(0.5)*nm)
    __shared__ h2     eh_s[NP][2];  // expvals (f16), [0]=(e0,e1) [1]=(e2,e3)
    __shared__ float4 pa_s[4 * NP]; // per-wave partial a (f32)
    __shared__ float  pd_s[4 * NP]; // per-wave partial deg (f32)
    __shared__ float4 feat_s[NP];
    __shared__ float  logit_s[NCLS];

    const h2 H_ONE  = {(_Float16)1.0f, (_Float16)1.0f};
    const h2 H_HALF = {(_Float16)0.5f, (_Float16)0.5f};
    const h2 H_ZERO = {(_Float16)0.0f, (_Float16)0.0f};

    const float* xb = x + (size_t)b * 784;
    const float* pb = phi + (size_t)b * 784;

    // ---- Phase 1 ----
    if (t < NP) {
        const int hp = t / 14, wp = t - hp * 14;
        const int r0 = hp * 2, c0 = wp * 2;
        float th0 = xb[r0 * 28 + c0];
        float th1 = xb[r0 * 28 + c0 + 1];
        float th2 = xb[(r0 + 1) * 28 + c0];
        float th3 = xb[(r0 + 1) * 28 + c0 + 1];
        float4 ph = *(const float4*)(pb + t * 4);
        float z0 = __cosf(th0) * __cosf(ph.x);
        float z1 = __cosf(th1) * __cosf(ph.y);
        float z2 = __cosf(th2) * __cosf(ph.z);
        float z3 = __cosf(th3) * __cosf(ph.w);
        float e0 = z0;
        float e1 = e0 * z1;
        float e2 = e1 * z2;
        float e3 = e2 * z3;
        e_s[t] = make_float4(e0, e1, e2, e3);
        eh_s[t][0] = (h2){(_Float16)e0, (_Float16)e1};
        eh_s[t][1] = (h2){(_Float16)e2, (_Float16)e3};
        float nn = sqrtf(e0 * e0 + e1 * e1 + e2 * e2 + e3 * e3) + 1e-12f;
        inv_s[t] = 1.0f / nn;
        thr_s[t] = make_float2(0.8944271909999159f * nn,   // sqrt(0.8)*nm
                               0.7071067811865476f * nn);  // sqrt(0.5)*nm
    }
    __syncthreads();

    // ---- Phase 2: main (all 64 lanes, 3 patches each, f16 packed body) ----
    const int m0 = wave * 49;
    {
        h2 qA[3], qB[3], aA[3], aB[3], dg[3];
        #pragma unroll
        for (int k = 0; k < 3; ++k) {
            const int n = lane + 64 * k;
            float4 q = e_s[n];
            float iv = inv_s[n];
            qA[k] = (h2){(_Float16)(q.x * iv), (_Float16)(q.y * iv)};
            qB[k] = (h2){(_Float16)(q.z * iv), (_Float16)(q.w * iv)};
            aA[k] = H_ZERO; aB[k] = H_ZERO; dg[k] = H_ZERO;
        }
        #pragma unroll 7
        for (int m = m0; m < m0 + 49; ++m) {
            h2 ea = eh_s[m][0];      // wave-uniform broadcast (b64 pair)
            h2 eb = eh_s[m][1];
            float2 th = thr_s[m];
            #pragma unroll
            for (int k = 0; k < 3; ++k) {
                float d  = dot4_h(qA[k], qB[k], ea, eb);
                float ad = fabsf(d);
                h2 w2 = (ad >= th.x) ? H_ONE : ((ad >= th.y) ? H_HALF : H_ZERO);
                dg[k] += w2;                 // v_pk_add_f16 (halves exact)
                aA[k] += w2 * ea;            // v_pk_fma_f16
                aB[k] += w2 * eb;            // v_pk_fma_f16
            }
        }
        #pragma unroll
        for (int k = 0; k < 3; ++k) {
            pa_s[wave * NP + lane + 64 * k] =
                make_float4((float)aA[k].x, (float)aA[k].y,
                            (float)aB[k].x, (float)aB[k].y);
            pd_s[wave * NP + lane + 64 * k] = (float)dg[k].x;
        }
    }

    // ---- Phase 2 tail: patches 192..195, m-sliced across 16 lane-groups ----
    {
        const int nt    = 192 + (lane & 3);
        const int slice = lane >> 2;
        float4 q = e_s[nt];
        float iv = inv_s[nt];
        h2 qa = (h2){(_Float16)(q.x * iv), (_Float16)(q.y * iv)};
        h2 qb = (h2){(_Float16)(q.z * iv), (_Float16)(q.w * iv)};
        h2 ta = H_ZERO, tb = H_ZERO, td = H_ZERO;
        for (int m = m0 + slice; m < m0 + 49; m += 16) {
            h2 ea = eh_s[m][0];
            h2 eb = eh_s[m][1];
            float2 th = thr_s[m];
            float d  = dot4_h(qa, qb, ea, eb);
            float ad = fabsf(d);
            h2 w2 = (ad >= th.x) ? H_ONE : ((ad >= th.y) ? H_HALF : H_ZERO);
            td += w2;
            ta += w2 * ea;
            tb += w2 * eb;
        }
        float ax = (float)ta.x, ay = (float)ta.y;
        float az = (float)tb.x, aw = (float)tb.y;
        float dt = (float)td.x;
        // butterfly over slices (offsets preserve lane&3)
        #pragma unroll
        for (int off = 4; off <= 32; off <<= 1) {
            ax += __shfl_xor(ax, off, 64);
            ay += __shfl_xor(ay, off, 64);
            az += __shfl_xor(az, off, 64);
            aw += __shfl_xor(aw, off, 64);
            dt += __shfl_xor(dt, off, 64);
        }
        if (lane < 4) {
            pa_s[wave * NP + 192 + lane] = make_float4(ax, ay, az, aw);
            pd_s[wave * NP + 192 + lane] = dt;
        }
    }
    __syncthreads();

    // ---- Phase 2b: combine partials, self-subtract, build feats ----
    if (t < NP) {
        float4 e  = e_s[t];
        float  iv = inv_s[t];
        float2 th = thr_s[t];
        float4 at = make_float4(0.f, 0.f, 0.f, 0.f);
        float  dt = 0.f;
        #pragma unroll
        for (int w = 0; w < 4; ++w) {
            float4 p = pa_s[w * NP + t];
            at.x += p.x; at.y += p.y; at.z += p.z; at.w += p.w;
            dt += pd_s[w * NP + t];
        }
        // self-edge: IDENTICAL fdot2 chain on identical f16 casts -> same w
        h2 ea = eh_s[t][0];
        h2 eb = eh_s[t][1];
        h2 qa = (h2){(_Float16)(e.x * iv), (_Float16)(e.y * iv)};
        h2 qb = (h2){(_Float16)(e.z * iv), (_Float16)(e.w * iv)};
        float d  = dot4_h(qa, qb, ea, eb);
        float ad = fabsf(d);
        float w  = (ad >= th.x) ? 1.0f : ((ad >= th.y) ? 0.5f : 0.0f);
        dt -= w;
        at.x -= w * e.x; at.y -= w * e.y; at.z -= w * e.z; at.w -= w * e.w;
        const float s = 1.0f + dt;   // smooth = I + D - W
        feat_s[t] = make_float4(s * e.x - at.x, s * e.y - at.y,
                                s * e.z - at.z, s * e.w - at.w);
    }
    __syncthreads();

    // ---- Phase 3: logits ----
    if (t < NCLS * 16) {
        const int j  = t >> 4;
        const int sl = t & 15;
        const float4* wr = (const float4*)(W + j * 784);
        float p = 0.f;
        for (int i = sl; i < NP; i += 16) {
            float4 f  = feat_s[i];
            float4 w4 = wr[i];
            p += f.x * w4.x + f.y * w4.y + f.z * w4.z + f.w * w4.w;
        }
        #pragma unroll
        for (int off = 8; off > 0; off >>= 1)
            p += __shfl_down(p, off, 16);
        if (sl == 0) logit_s[j] = p + bl[j];
    }
    __syncthreads();

    // ---- Phase 4: log_softmax ----
    if (t < NCLS) {
        float mx = -INFINITY;
        #pragma unroll
        for (int j = 0; j < NCLS; ++j) mx = fmaxf(mx, logit_s[j]);
        float sum = 0.f;
        #pragma unroll
        for (int j = 0; j < NCLS; ++j) sum += expf(logit_s[j] - mx);
        out[(size_t)b * NCLS + t] = logit_s[t] - mx - logf(sum);
    }
}

extern "C" void kernel_launch(void* const* d_in, const int* in_sizes, int n_in,
                              void* d_out, int out_size, void* d_ws, size_t ws_size,
                              hipStream_t stream) {
    const float* x   = (const float*)d_in[0];   // [B,1,28,28]
    const float* phi = (const float*)d_in[1];   // [B,196,4]
    const float* W   = (const float*)d_in[2];   // [10,784]
    const float* bl  = (const float*)d_in[3];   // [10]
    float* out = (float*)d_out;                 // [B,10]

    const int B = in_sizes[0] / 784;
    quanv_fused_kernel<<<dim3(B), dim3(256), 0, stream>>>(x, phi, W, bl, out);
}